// Round 1
// baseline (1060.455 us; speedup 1.0000x reference)
//
#include <hip/hip_runtime.h>

#define NN 100000
#define NE 5000000
#define NB 16
#define NLAYER 4

// h[n*16+b] = x[n*16+b] * tw[ct[n]] + tb[ct[n]]
__global__ void type_affine(const float* __restrict__ x,
                            const float* __restrict__ tw,
                            const float* __restrict__ tb,
                            const int* __restrict__ ct,
                            float* __restrict__ h) {
    int idx = blockIdx.x * blockDim.x + threadIdx.x;
    if (idx >= NN * NB) return;
    int n = idx >> 4;
    int t = ct[n];
    h[idx] = x[idx] * tw[t] + tb[t];
}

// one thread per (edge, batch): 16 lanes share an edge (broadcast loads),
// gather a contiguous 64B h-segment, scatter-add a contiguous 64B segment.
__global__ void spmm_edges(const int* __restrict__ rows,
                           const int* __restrict__ cols,
                           const float* __restrict__ w,
                           const float* __restrict__ h_in,
                           float* __restrict__ h_out) {
    long long idx = (long long)blockIdx.x * blockDim.x + threadIdx.x;
    if (idx >= (long long)NE * NB) return;
    int e = (int)(idx >> 4);
    int b = (int)(idx & 15);
    int r = rows[e];
    int c = cols[e];
    float v = w[e] * h_in[c * NB + b];
    atomicAdd(&h_out[r * NB + b], v);
}

// out[b] = sum_d dm_vals[d]*fc_w[d]*h[dm_cols[d]*16+b] + fc_b
__global__ void final_fc(const float* __restrict__ dmv,
                         const int* __restrict__ dmc,
                         const float* __restrict__ fcw,
                         const float* __restrict__ fcb,
                         const float* __restrict__ h,
                         float* __restrict__ out) {
    __shared__ float red[NB];
    int t = threadIdx.x;  // 512 threads, one per decision neuron
    if (t < NB) red[t] = 0.f;
    __syncthreads();
    float wd = dmv[t] * fcw[t];
    int c = dmc[t];
    for (int b = 0; b < NB; ++b) {
        float v = wd * h[c * NB + b];
        // 64-lane wave reduce, then one shared atomic per wave
        for (int off = 32; off; off >>= 1) v += __shfl_down(v, off);
        if ((t & 63) == 0) atomicAdd(&red[b], v);
    }
    __syncthreads();
    if (t < NB) out[t] = red[t] + fcb[0];
}

extern "C" void kernel_launch(void* const* d_in, const int* in_sizes, int n_in,
                              void* d_out, int out_size, void* d_ws, size_t ws_size,
                              hipStream_t stream) {
    const float* x   = (const float*)d_in[0];
    const float* tw  = (const float*)d_in[1];
    const float* tb  = (const float*)d_in[2];
    const float* ew  = (const float*)d_in[3];
    const float* dmv = (const float*)d_in[4];
    const float* fcw = (const float*)d_in[5];
    const float* fcb = (const float*)d_in[6];
    const int* ct  = (const int*)d_in[7];
    const int* er  = (const int*)d_in[8];
    const int* ec  = (const int*)d_in[9];
    const int* dmc = (const int*)d_in[10];
    float* out = (float*)d_out;

    float* h0 = (float*)d_ws;
    float* h1 = h0 + (size_t)NN * NB;

    type_affine<<<(NN * NB + 255) / 256, 256, 0, stream>>>(x, tw, tb, ct, h0);

    float* cur = h0;
    float* nxt = h1;
    for (int l = 0; l < NLAYER; ++l) {
        hipMemsetAsync(nxt, 0, (size_t)NN * NB * sizeof(float), stream);
        long long total = (long long)NE * NB;
        int blocks = (int)((total + 255) / 256);
        spmm_edges<<<blocks, 256, 0, stream>>>(er, ec, ew, cur, nxt);
        float* tmp = cur; cur = nxt; nxt = tmp;
    }

    final_fc<<<1, 512, 0, stream>>>(dmv, dmc, fcw, fcb, cur, out);
}